// Round 1
// baseline (820.468 us; speedup 1.0000x reference)
//
#include <hip/hip_runtime.h>
#include <cfloat>

// NearestNeighborGraph: S=16 samples, N=2048 points, D=64 dims, K=16.
// d[i,j] = x2_i + x2_j - 2<h_i,h_j>; per-row top-16 smallest (lowest-index ties).
// Outputs (all written as float32 into one flat buffer, per harness read path):
//   [0 .. S*N*K)        knn_dist
//   [S*N*K .. 2*S*N*K)  dst = knn index + s*N
//   [2*S*N*K .. 3*S*N*K) src = row global id

constexpr int NS = 16;
constexpr int NP = 2048;
constexpr int ND = 64;
constexpr int KK = 16;
constexpr int ROWS_PER_BLOCK = 128;   // block = 256 threads: 128 rows x 2 j-halves
constexpr int CHUNK = 64;             // j's per half staged per step
constexpr int NSTEP = (NP / 2) / CHUNK;

__global__ __launch_bounds__(256, 1)
void knn_kernel(const float* __restrict__ h, float* __restrict__ out)
{
    __shared__ float4 ldsH[2 * CHUNK * 16];  // 128 staged rows x 64 floats = 32 KB
    __shared__ float  ldsX2[2 * CHUNK];

    const int t    = threadIdx.x;
    const int b    = blockIdx.x;
    const int s    = b >> 4;              // sample
    const int rb   = b & 15;              // row block within sample
    const int r    = t & 127;             // local row
    const int half = t >> 7;              // which j-half this thread scans
    const int row  = rb * ROWS_PER_BLOCK + r;
    const float* __restrict__ hs = h + (size_t)s * NP * ND;

    // own row into registers (64 floats)
    float4 hi[16];
    {
        const float4* hrow = (const float4*)(hs + row * ND);
        #pragma unroll
        for (int k = 0; k < 16; ++k) hi[k] = hrow[k];
    }

    // ||h_i||^2 with 4 accumulator chains
    float x2i;
    {
        float a0 = 0.f, a1 = 0.f, a2 = 0.f, a3 = 0.f;
        #pragma unroll
        for (int k = 0; k < 16; ++k) {
            a0 = fmaf(hi[k].x, hi[k].x, a0);
            a1 = fmaf(hi[k].y, hi[k].y, a1);
            a2 = fmaf(hi[k].z, hi[k].z, a2);
            a3 = fmaf(hi[k].w, hi[k].w, a3);
        }
        x2i = (a0 + a1) + (a2 + a3);
    }

    // sorted ascending top-K list in registers (fully unrolled accesses only)
    float dist[KK];
    int   idx [KK];
    #pragma unroll
    for (int k = 0; k < KK; ++k) { dist[k] = FLT_MAX; idx[k] = 0; }

    for (int c = 0; c < NSTEP; ++c) {
        __syncthreads();   // protect LDS from previous step's readers
        // stage CHUNK rows for each half (coalesced: consecutive lanes ->
        // consecutive float4s)
        const int jA = c * CHUNK;
        const int jB = NP / 2 + c * CHUNK;
        #pragma unroll
        for (int k = 0; k < 8; ++k) {
            int f  = t + k * 256;         // float4 slot 0..2047
            int rr = f >> 4;              // staged row 0..127
            int pc = f & 15;
            int gj = (rr < CHUNK) ? (jA + rr) : (jB + (rr - CHUNK));
            ldsH[f] = ((const float4*)(hs + gj * ND))[pc];
        }
        __syncthreads();
        // ||h_j||^2 for the 128 staged rows (phase-swizzled to spread banks)
        if (t < 2 * CHUNK) {
            float a0 = 0.f, a1 = 0.f, a2 = 0.f, a3 = 0.f;
            #pragma unroll
            for (int k = 0; k < 16; ++k) {
                int pc = (k + t) & 15;
                float4 v = ldsH[t * 16 + pc];
                a0 = fmaf(v.x, v.x, a0); a1 = fmaf(v.y, v.y, a1);
                a2 = fmaf(v.z, v.z, a2); a3 = fmaf(v.w, v.w, a3);
            }
            ldsX2[t] = (a0 + a1) + (a2 + a3);
        }
        __syncthreads();

        // wave-uniform pointers (half is constant per wave) -> broadcast ds_reads
        const float4* __restrict__ hb  = &ldsH[half * CHUNK * 16];
        const float*  __restrict__ x2b = &ldsX2[half * CHUNK];
        const int jbase = half ? jB : jA;

        #pragma unroll 2
        for (int jj = 0; jj < CHUNK; ++jj) {
            const float4* hv = &hb[jj * 16];
            float a0 = 0.f, a1 = 0.f, a2 = 0.f, a3 = 0.f;
            #pragma unroll
            for (int k = 0; k < 16; ++k) {
                float4 v = hv[k];
                a0 = fmaf(hi[k].x, v.x, a0);
                a1 = fmaf(hi[k].y, v.y, a1);
                a2 = fmaf(hi[k].z, v.z, a2);
                a3 = fmaf(hi[k].w, v.w, a3);
            }
            float dotv = (a0 + a1) + (a2 + a3);
            // 2*dot is exact in fp32, so this matches np's (x2i+x2j) - 2*dot
            float d2 = fmaf(-2.0f, dotv, x2i + x2b[jj]);
            if (d2 < dist[KK - 1]) {          // strict < : lowest-index tie-break
                int j = jbase + jj;
                #pragma unroll
                for (int p = KK - 1; p > 0; --p) {
                    bool sh = d2 < dist[p - 1];
                    bool he = d2 < dist[p];
                    float nd = sh ? dist[p - 1] : (he ? d2 : dist[p]);
                    int   ni = sh ? idx[p - 1]  : (he ? j  : idx[p]);
                    dist[p] = nd; idx[p] = ni;
                }
                if (d2 < dist[0]) { dist[0] = d2; idx[0] = j; }
            }
        }
    }

    // merge the two halves per row (B indices all > A indices; strict < keeps
    // the lowest-index-first ordering on exact ties)
    __syncthreads();
    float* mdist = (float*)ldsH;                       // 128*16 floats
    int*   midx  = (int*)(mdist + ROWS_PER_BLOCK * KK);
    if (half) {
        #pragma unroll
        for (int k = 0; k < KK; ++k) {
            mdist[r * KK + k] = dist[k];
            midx [r * KK + k] = idx[k];
        }
    }
    __syncthreads();
    if (!half) {
        #pragma unroll
        for (int k = 0; k < KK; ++k) {
            float d2 = mdist[r * KK + k];
            int   j  = midx [r * KK + k];
            if (d2 < dist[KK - 1]) {
                #pragma unroll
                for (int p = KK - 1; p > 0; --p) {
                    bool sh = d2 < dist[p - 1];
                    bool he = d2 < dist[p];
                    float nd = sh ? dist[p - 1] : (he ? d2 : dist[p]);
                    int   ni = sh ? idx[p - 1]  : (he ? j  : idx[p]);
                    dist[p] = nd; idx[p] = ni;
                }
                if (d2 < dist[0]) { dist[0] = d2; idx[0] = j; }
            }
        }
        // emit outputs (everything as float32 in one flat buffer)
        const size_t rg   = (size_t)s * NP + row;
        float* oknn = out + rg * KK;
        float* odst = out + (size_t)NS * NP * KK + rg * KK;
        float* osrc = out + (size_t)2 * NS * NP * KK + rg * KK;
        const int   off  = s * NP;
        const float srcv = (float)(off + row);
        #pragma unroll
        for (int k = 0; k < KK; ++k) oknn[k] = dist[k];
        #pragma unroll
        for (int k = 0; k < KK; ++k) odst[k] = (float)(idx[k] + off);
        #pragma unroll
        for (int k = 0; k < KK; ++k) osrc[k] = srcv;
    }
}

extern "C" void kernel_launch(void* const* d_in, const int* in_sizes, int n_in,
                              void* d_out, int out_size, void* d_ws, size_t ws_size,
                              hipStream_t stream)
{
    const float* h = (const float*)d_in[0];
    float* out = (float*)d_out;
    // d_in[1] is K (=16), compile-time constant here.
    dim3 grid(NS * (NP / ROWS_PER_BLOCK));   // 256 blocks
    dim3 block(256);
    hipLaunchKernelGGL(knn_kernel, grid, block, 0, stream, h, out);
}

// Round 2
// 454.552 us; speedup vs baseline: 1.8050x; 1.8050x over previous
//
#include <hip/hip_runtime.h>
#include <cfloat>

// NearestNeighborGraph: S=16, N=2048, D=64, K=16.
// Round-2 restructure:
//  - hv (row j) + x2j read via wave-uniform SCALAR loads (s_load) -> no LDS
//    staging pipe pressure, no ds_read_b128 per j.
//  - top-16 insert deferred through a per-lane LDS candidate buffer; the
//    expensive shift-insert runs only on drains (~90/wave vs ~930 before).
//  - block = 64 rows x 4 j-quarter waves, grid 512 = 2 blocks/CU = 2 waves/SIMD.
//  - x2[j] precomputed by kernel1 with round-1's exact rotated summation order
//    ((k + (j&15)) & 15) so all d2 values are bit-identical to the passing
//    round-1 kernel (same flips, same absmax).

typedef float f16v __attribute__((ext_vector_type(16)));

constexpr int NS = 16, NP = 2048, ND = 64, KK = 16;
constexpr int NQ  = 4;           // j-quarters == waves per block
constexpr int JQ  = NP / NQ;     // 512 j's per quarter
constexpr int BUF = 8;           // candidate slots per lane
constexpr int PSTR = 17;         // publish stride (bank spread)

__global__ void x2_kernel(const float* __restrict__ h, float* __restrict__ x2)
{
    int g = blockIdx.x * 256 + threadIdx.x;          // 0 .. NS*NP-1
    const float4* row = (const float4*)(h + (size_t)g * ND);
    int ph = g & 15;                                  // == (j % NP) & 15
    float a0 = 0.f, a1 = 0.f, a2 = 0.f, a3 = 0.f;
    #pragma unroll
    for (int k = 0; k < 16; ++k) {
        float4 v = row[(k + ph) & 15];               // round-1's rotated order
        a0 = fmaf(v.x, v.x, a0); a1 = fmaf(v.y, v.y, a1);
        a2 = fmaf(v.z, v.z, a2); a3 = fmaf(v.w, v.w, a3);
    }
    x2[g] = (a0 + a1) + (a2 + a3);
}

__device__ __forceinline__ void insert16(float (&dist)[KK], int (&idx)[KK],
                                         float d2, int j)
{
    #pragma unroll
    for (int p = KK - 1; p > 0; --p) {
        bool sh = d2 < dist[p - 1];
        bool he = d2 < dist[p];
        float nd = sh ? dist[p - 1] : (he ? d2 : dist[p]);
        int   ni = sh ? idx[p - 1]  : (he ? j  : idx[p]);
        dist[p] = nd; idx[p] = ni;
    }
    if (d2 < dist[0]) { dist[0] = d2; idx[0] = j; }
}

__global__ __launch_bounds__(256, 2)
void knn_main(const float* __restrict__ h, const float* __restrict__ x2g,
              float* __restrict__ out)
{
    __shared__ float bufd[BUF * 256];    // [slot][thread] : bank = t&31, 2-way = free
    __shared__ int   bufi[BUF * 256];
    __shared__ float pubd[2][64 * PSTR];
    __shared__ int   pubi[2][64 * PSTR];

    const int t  = threadIdx.x;
    const int r  = t & 63;               // lane = row
    const int q  = t >> 6;               // wave = j-quarter
    const int s  = blockIdx.x >> 5;
    const int rb = blockIdx.x & 31;
    const int row = rb * 64 + r;
    const float* __restrict__ hs = h + (size_t)s * NP * ND;

    // own row (i) into registers
    float4 hi[16];
    {
        const float4* hrow = (const float4*)(hs + row * ND);
        #pragma unroll
        for (int k = 0; k < 16; ++k) hi[k] = hrow[k];
    }
    // x2i: ascending 4-chain (identical to round 1)
    float x2i;
    {
        float a0 = 0.f, a1 = 0.f, a2 = 0.f, a3 = 0.f;
        #pragma unroll
        for (int k = 0; k < 16; ++k) {
            a0 = fmaf(hi[k].x, hi[k].x, a0);
            a1 = fmaf(hi[k].y, hi[k].y, a1);
            a2 = fmaf(hi[k].z, hi[k].z, a2);
            a3 = fmaf(hi[k].w, hi[k].w, a3);
        }
        x2i = (a0 + a1) + (a2 + a3);
    }

    float dist[KK]; int idx[KK];
    #pragma unroll
    for (int k = 0; k < KK; ++k) { dist[k] = FLT_MAX; idx[k] = 0; }

    // wave-uniform (scalar) bases so hv/x2j compile to s_load
    const int jbase = __builtin_amdgcn_readfirstlane(q * JQ);
    const f16v*  __restrict__ hq  = (const f16v*)(hs + (size_t)jbase * ND);
    const float* __restrict__ x2q = x2g + s * NP + jbase;

    int cnt = 0;
    for (int jj = 0; jj < JQ; ++jj) {
        const f16v c0 = hq[jj * 4 + 0];
        const f16v c1 = hq[jj * 4 + 1];
        const f16v c2 = hq[jj * 4 + 2];
        const f16v c3 = hq[jj * 4 + 3];
        const float x2j = x2q[jj];

        float a0 = 0.f, a1 = 0.f, a2 = 0.f, a3 = 0.f;
        #pragma unroll
        for (int k = 0; k < 4; ++k) {
            a0 = fmaf(hi[k].x, c0[4 * k + 0], a0);
            a1 = fmaf(hi[k].y, c0[4 * k + 1], a1);
            a2 = fmaf(hi[k].z, c0[4 * k + 2], a2);
            a3 = fmaf(hi[k].w, c0[4 * k + 3], a3);
        }
        #pragma unroll
        for (int k = 0; k < 4; ++k) {
            a0 = fmaf(hi[4 + k].x, c1[4 * k + 0], a0);
            a1 = fmaf(hi[4 + k].y, c1[4 * k + 1], a1);
            a2 = fmaf(hi[4 + k].z, c1[4 * k + 2], a2);
            a3 = fmaf(hi[4 + k].w, c1[4 * k + 3], a3);
        }
        #pragma unroll
        for (int k = 0; k < 4; ++k) {
            a0 = fmaf(hi[8 + k].x, c2[4 * k + 0], a0);
            a1 = fmaf(hi[8 + k].y, c2[4 * k + 1], a1);
            a2 = fmaf(hi[8 + k].z, c2[4 * k + 2], a2);
            a3 = fmaf(hi[8 + k].w, c2[4 * k + 3], a3);
        }
        #pragma unroll
        for (int k = 0; k < 4; ++k) {
            a0 = fmaf(hi[12 + k].x, c3[4 * k + 0], a0);
            a1 = fmaf(hi[12 + k].y, c3[4 * k + 1], a1);
            a2 = fmaf(hi[12 + k].z, c3[4 * k + 2], a2);
            a3 = fmaf(hi[12 + k].w, c3[4 * k + 3], a3);
        }
        float dotv = (a0 + a1) + (a2 + a3);
        float d2 = fmaf(-2.0f, dotv, x2i + x2j);

        // branch-free push: always write slot cnt, bump cnt only on hit
        bufd[cnt * 256 + t] = d2;
        bufi[cnt * 256 + t] = jbase + jj;
        cnt += (d2 < dist[KK - 1]) ? 1 : 0;

        if (__any(cnt == BUF)) {          // wave-converged drain
            #pragma unroll 1
            for (int k = 0; k < BUF; ++k) {
                if (!__any(k < cnt)) break;
                bool  act = k < cnt;
                float dd  = bufd[k * 256 + t];
                int   dj  = bufi[k * 256 + t];
                insert16(dist, idx, act ? dd : FLT_MAX, dj);
            }
            cnt = 0;
        }
    }
    // final drain
    #pragma unroll 1
    for (int k = 0; k < BUF; ++k) {
        if (!__any(k < cnt)) break;
        bool  act = k < cnt;
        float dd  = bufd[k * 256 + t];
        int   dj  = bufi[k * 256 + t];
        insert16(dist, idx, act ? dd : FLT_MAX, dj);
    }

    // tree-merge the 4 quarter lists (lane r = row r throughout)
    __syncthreads();
    if (q == 1 || q == 3) {
        int sec = q >> 1;
        #pragma unroll
        for (int k = 0; k < KK; ++k) {
            pubd[sec][r * PSTR + k] = dist[k];
            pubi[sec][r * PSTR + k] = idx[k];
        }
    }
    __syncthreads();
    if (q == 0 || q == 2) {
        int sec = q >> 1;
        #pragma unroll 1
        for (int k = 0; k < KK; ++k)
            insert16(dist, idx, pubd[sec][r * PSTR + k], pubi[sec][r * PSTR + k]);
    }
    __syncthreads();
    if (q == 2) {
        #pragma unroll
        for (int k = 0; k < KK; ++k) {
            pubd[0][r * PSTR + k] = dist[k];
            pubi[0][r * PSTR + k] = idx[k];
        }
    }
    __syncthreads();
    if (q == 0) {
        #pragma unroll 1
        for (int k = 0; k < KK; ++k)
            insert16(dist, idx, pubd[0][r * PSTR + k], pubi[0][r * PSTR + k]);

        const size_t rg = (size_t)s * NP + row;
        float* oknn = out + rg * KK;
        float* odst = out + (size_t)NS * NP * KK + rg * KK;
        float* osrc = out + (size_t)2 * NS * NP * KK + rg * KK;
        const int off = s * NP;
        #pragma unroll
        for (int k = 0; k < KK; ++k) oknn[k] = dist[k];
        #pragma unroll
        for (int k = 0; k < KK; ++k) odst[k] = (float)(idx[k] + off);
        #pragma unroll
        for (int k = 0; k < KK; ++k) osrc[k] = (float)(off + row);
    }
}

extern "C" void kernel_launch(void* const* d_in, const int* in_sizes, int n_in,
                              void* d_out, int out_size, void* d_ws, size_t ws_size,
                              hipStream_t stream)
{
    const float* h  = (const float*)d_in[0];
    float* x2       = (float*)d_ws;          // NS*NP floats = 128 KB scratch
    float* out      = (float*)d_out;
    hipLaunchKernelGGL(x2_kernel, dim3(NS * NP / 256), dim3(256), 0, stream, h, x2);
    hipLaunchKernelGGL(knn_main,  dim3(NS * NP / 64),  dim3(256), 0, stream, h, x2, out);
}